// Round 2
// baseline (14349.797 us; speedup 1.0000x reference)
//
#include <hip/hip_runtime.h>

#define EPI_F32 0
#define EPI_BF16 1
#define EPI_LSTM1 2
#define EPI_LSTM2 3
#define EPI_LOGITS 4

#define T_ 40
#define VOC_ 10000

typedef __attribute__((ext_vector_type(8))) short bf16x8;
typedef __attribute__((ext_vector_type(4))) short short4v;
typedef __attribute__((ext_vector_type(8))) short short8v;
typedef __attribute__((ext_vector_type(4))) float float4v;
typedef __attribute__((ext_vector_type(4))) float f32x4;

__device__ __forceinline__ float bf2f(short s) {
  unsigned u = ((unsigned)(unsigned short)s) << 16;
  float f; __builtin_memcpy(&f, &u, 4); return f;
}
__device__ __forceinline__ short f2bf(float f) {
  unsigned u; __builtin_memcpy(&u, &f, 4);
  u += 0x7FFFu + ((u >> 16) & 1u);
  return (short)(u >> 16);
}
__device__ __forceinline__ float sigm(float x) { return 1.f / (1.f + expf(-x)); }

// ---------------- one-time conversion / packing kernels ----------------

__global__ __launch_bounds__(256) void k_f2bf(const float* __restrict__ s, short* __restrict__ d, long n4) {
  long i = (long)blockIdx.x * 256 + threadIdx.x;
  long stride = (long)gridDim.x * 256;
  for (; i < n4; i += stride) {
    float4v f = ((const float4v*)s)[i];
    short4v o;
    #pragma unroll
    for (int j = 0; j < 4; j++) o[j] = f2bf(f[j]);
    ((short4v*)d)[i] = o;
  }
}

// split f32 -> bf16 hi + bf16 lo (lo = bf16(x - f32(hi)))
__global__ __launch_bounds__(256) void k_f2bf_split(const float* __restrict__ s,
    short* __restrict__ dh, short* __restrict__ dl, long n4) {
  long i = (long)blockIdx.x * 256 + threadIdx.x;
  long stride = (long)gridDim.x * 256;
  for (; i < n4; i += stride) {
    float4v f = ((const float4v*)s)[i];
    short4v oh, ol;
    #pragma unroll
    for (int j = 0; j < 4; j++) {
      short h = f2bf(f[j]);
      oh[j] = h;
      ol[j] = f2bf(f[j] - bf2f(h));
    }
    ((short4v*)dh)[i] = oh;
    ((short4v*)dl)[i] = ol;
  }
}

// dst[p, c] (bf16, [4096 x Ktot]) gate-interleaved row perm p=4h+g -> orig row g*1024+h, single plane.
__global__ __launch_bounds__(256) void k_perm_w(short* __restrict__ dst,
    const float* __restrict__ s1, int ld1, int col0, int K1,
    const float* __restrict__ s2, int ld2, int Ktot) {
  int K4 = Ktot >> 2;
  long n4 = 4096L * K4;
  long i = (long)blockIdx.x * 256 + threadIdx.x;
  long stride = (long)gridDim.x * 256;
  for (; i < n4; i += stride) {
    int p = (int)(i / K4);
    int c = ((int)(i % K4)) << 2;
    int orig = ((p & 3) << 10) + (p >> 2);
    const float* src = (c < K1) ? (s1 + (long)orig * ld1 + col0 + c)
                                : (s2 + (long)orig * ld2 + (c - K1));
    float4v f = *(const float4v*)src;
    short4v o;
    #pragma unroll
    for (int j = 0; j < 4; j++) o[j] = f2bf(f[j]);
    *(short4v*)(dst + (long)p * Ktot + c) = o;
  }
}

// split variant: hi and lo planes
__global__ __launch_bounds__(256) void k_perm_w_split(short* __restrict__ dh, short* __restrict__ dl,
    const float* __restrict__ s1, int ld1, int col0, int K1,
    const float* __restrict__ s2, int ld2, int Ktot) {
  int K4 = Ktot >> 2;
  long n4 = 4096L * K4;
  long i = (long)blockIdx.x * 256 + threadIdx.x;
  long stride = (long)gridDim.x * 256;
  for (; i < n4; i += stride) {
    int p = (int)(i / K4);
    int c = ((int)(i % K4)) << 2;
    int orig = ((p & 3) << 10) + (p >> 2);
    const float* src = (c < K1) ? (s1 + (long)orig * ld1 + col0 + c)
                                : (s2 + (long)orig * ld2 + (c - K1));
    float4v f = *(const float4v*)src;
    short4v oh, ol;
    #pragma unroll
    for (int j = 0; j < 4; j++) {
      short h = f2bf(f[j]);
      oh[j] = h;
      ol[j] = f2bf(f[j] - bf2f(h));
    }
    *(short4v*)(dh + (long)p * Ktot + c) = oh;
    *(short4v*)(dl + (long)p * Ktot + c) = ol;
  }
}

__global__ __launch_bounds__(256) void k_perm_bias(float* __restrict__ d1, const float* __restrict__ s1,
                                                   float* __restrict__ d2, const float* __restrict__ s2) {
  int p = blockIdx.x * 256 + threadIdx.x;
  if (p < 4096) {
    int orig = ((p & 3) << 10) + (p >> 2);
    d1[p] = s1[orig];
    d2[p] = s2[orig];
  }
}

// embeddings gather: A_emb[b*T+t, :] = bf16(embed_W[captions[b,t], :])
__global__ __launch_bounds__(256) void k_gather_emb(short* __restrict__ dst, const float* __restrict__ embW,
                                                    const int* __restrict__ cap) {
  int i = blockIdx.x * 256 + threadIdx.x;  // 5120*128
  if (i >= 5120 * 128) return;
  int row = i >> 7, c8 = (i & 127) << 3;
  int tok = cap[row];
  const float4v* s = (const float4v*)(embW + (long)tok * 1024 + c8);
  float4v f0 = s[0], f1 = s[1];
  short8v o;
  #pragma unroll
  for (int j = 0; j < 4; j++) { o[j] = f2bf(f0[j]); o[4 + j] = f2bf(f1[j]); }
  *(short8v*)(dst + (long)row * 1024 + c8) = o;
}

// ---------------- generic MFMA GEMM: C[M,N] = A[M,K](bf16 hi/lo) @ W[N,K]^T(bf16 hi/lo) ----------
// MT=128 (blockIdx.x = m-tile), NT cols per block (blockIdx.y), 4 waves; wave w owns m-frags
// {2w, 2w+1} x all n-frags. SA: add Alo@W; SW: add A@Wlo (3-term split ~= f32 precision).

template<int NT, int EPI, bool NBOUND, bool SA, bool SW>
__global__ __launch_bounds__(256) void gemm_k(
    const short* __restrict__ A, const short* __restrict__ Alo,
    const short* __restrict__ W, const short* __restrict__ Wlo,
    int K, int lda, int N,
    void* __restrict__ out, const float* __restrict__ bias,
    const float* __restrict__ zuv, const short* __restrict__ zemb,
    float* __restrict__ cstate,
    const short* __restrict__ xcur_hi, const short* __restrict__ xcur_lo,
    short* __restrict__ xnext_hi, short* __restrict__ xnext_lo,
    short* __restrict__ x2_hi, short* __restrict__ x2_lo,
    short* __restrict__ h2n_hi, short* __restrict__ h2n_lo,
    const int* __restrict__ lengths, int t,
    const float* __restrict__ bl, float* __restrict__ out_logits) {
  constexpr int NF = NT / 16;
  const int lane = threadIdx.x & 63;
  const int wave = threadIdx.x >> 6;
  const int rif = lane & 15;   // row within fragment
  const int kg = lane >> 4;    // k-group 0..3
  const int m0 = blockIdx.x * 128;
  const int n0 = blockIdx.y * NT;

  f32x4 acc[2][NF];
  #pragma unroll
  for (int mf = 0; mf < 2; mf++)
    #pragma unroll
    for (int nf = 0; nf < NF; nf++) acc[mf][nf] = (f32x4){0.f, 0.f, 0.f, 0.f};

  const long arow = (long)(m0 + wave * 32 + rif) * lda + kg * 8;
  const short* a0p = A + arow;
  const short* a1p = a0p + 16 * (long)lda;
  const short* a0lp = SA ? (Alo + arow) : nullptr;
  const short* a1lp = SA ? (a0lp + 16 * (long)lda) : nullptr;
  const short* wp[NF];
  const short* wlp[NF];
  #pragma unroll
  for (int nf = 0; nf < NF; nf++) {
    int r = n0 + nf * 16 + rif;
    if (NBOUND && r >= N) r = 0;  // clamp; result unstored
    wp[nf] = W + (long)r * K + kg * 8;
    if (SW) wlp[nf] = Wlo + (long)r * K + kg * 8;
  }
  #pragma unroll 2
  for (int k = 0; k < K; k += 32) {
    bf16x8 a0 = *(const bf16x8*)(a0p + k);
    bf16x8 a1 = *(const bf16x8*)(a1p + k);
    bf16x8 a0l, a1l;
    if constexpr (SA) { a0l = *(const bf16x8*)(a0lp + k); a1l = *(const bf16x8*)(a1lp + k); }
    #pragma unroll
    for (int nf = 0; nf < NF; nf++) {
      bf16x8 b = *(const bf16x8*)(wp[nf] + k);
      acc[0][nf] = __builtin_amdgcn_mfma_f32_16x16x32_bf16(a0, b, acc[0][nf], 0, 0, 0);
      acc[1][nf] = __builtin_amdgcn_mfma_f32_16x16x32_bf16(a1, b, acc[1][nf], 0, 0, 0);
      if constexpr (SA) {
        acc[0][nf] = __builtin_amdgcn_mfma_f32_16x16x32_bf16(a0l, b, acc[0][nf], 0, 0, 0);
        acc[1][nf] = __builtin_amdgcn_mfma_f32_16x16x32_bf16(a1l, b, acc[1][nf], 0, 0, 0);
      }
      if constexpr (SW) {
        bf16x8 bl8 = *(const bf16x8*)(wlp[nf] + k);
        acc[0][nf] = __builtin_amdgcn_mfma_f32_16x16x32_bf16(a0, bl8, acc[0][nf], 0, 0, 0);
        acc[1][nf] = __builtin_amdgcn_mfma_f32_16x16x32_bf16(a1, bl8, acc[1][nf], 0, 0, 0);
      }
    }
  }

  if constexpr (EPI == EPI_F32 || EPI == EPI_BF16) {
    #pragma unroll
    for (int mf = 0; mf < 2; mf++)
      #pragma unroll
      for (int nf = 0; nf < NF; nf++)
        #pragma unroll
        for (int j = 0; j < 4; j++) {
          int row = m0 + wave * 32 + mf * 16 + kg * 4 + j;  // C/D: row=(lane>>4)*4+j
          int col = n0 + nf * 16 + rif;                     //      col=lane&15
          float v = acc[mf][nf][j];
          if (bias) v += bias[col];
          if constexpr (EPI == EPI_F32) ((float*)out)[(long)row * N + col] = v;
          else ((short*)out)[(long)row * N + col] = f2bf(v);
        }
  } else if constexpr (EPI == EPI_LOGITS) {
    #pragma unroll
    for (int mf = 0; mf < 2; mf++)
      #pragma unroll
      for (int nf = 0; nf < NF; nf++) {
        int col = n0 + nf * 16 + rif;  // vocab index
        if (!NBOUND || col < N) {
          #pragma unroll
          for (int j = 0; j < 4; j++) {
            int b = wave * 32 + mf * 16 + kg * 4 + j;  // batch (m0==0)
            bool act = lengths[b] > t;
            float v = act ? (acc[mf][nf][j] + bl[col]) : 0.f;
            out_logits[(long)b * (T_ * VOC_) + (long)t * VOC_ + col] = v;
          }
        }
      }
  } else {
    // LSTM epilogue (NT=32; perm cols p = 4h+g). Round-trip acc through LDS so each
    // thread gets all 4 gates of one (b,h).
    __shared__ float lds[128 * 33];
    #pragma unroll
    for (int mf = 0; mf < 2; mf++)
      #pragma unroll
      for (int nf = 0; nf < NF; nf++)
        #pragma unroll
        for (int j = 0; j < 4; j++) {
          int row = wave * 32 + mf * 16 + kg * 4 + j;
          int col = nf * 16 + rif;
          lds[row * 33 + col] = acc[mf][nf][j];
        }
    __syncthreads();
    #pragma unroll
    for (int it = 0; it < 4; it++) {
      int id = it * 256 + threadIdx.x;   // 1024 = 128 b x 8 h
      int b = id >> 3, hl = id & 7;
      int h = (n0 >> 2) + hl;
      int p = n0 + hl * 4;
      float gi = lds[b * 33 + hl * 4 + 0];
      float gf = lds[b * 33 + hl * 4 + 1];
      float gg = lds[b * 33 + hl * 4 + 2];
      float go = lds[b * 33 + hl * 4 + 3];
      if constexpr (EPI == EPI_LSTM1) {
        long zi = (long)b * 4096 + p;
        long ze = ((long)b * T_ + t) * 4096 + p;
        gi += zuv[zi + 0] + bf2f(zemb[ze + 0]);   // zuv already includes b1
        gf += zuv[zi + 1] + bf2f(zemb[ze + 1]);
        gg += zuv[zi + 2] + bf2f(zemb[ze + 2]);
        go += zuv[zi + 3] + bf2f(zemb[ze + 3]);
      } else {
        gi += bias[p + 0]; gf += bias[p + 1]; gg += bias[p + 2]; go += bias[p + 3];
      }
      float co = cstate[b * 1024 + h];
      float cn = sigm(gf) * co + sigm(gi) * tanhf(gg);
      float hn = sigm(go) * tanhf(cn);
      bool act = lengths[b] > t;
      cstate[b * 1024 + h] = act ? cn : co;
      short hi16 = f2bf(hn);
      short lo16 = f2bf(hn - bf2f(hi16));
      if constexpr (EPI == EPI_LSTM1) {
        x2_hi[b * 4096 + 2048 + h] = hi16;                      // h1n (fresh) for attn/gates2
        x2_lo[b * 4096 + 2048 + h] = lo16;
        short oh = xcur_hi[b * 2048 + 1024 + h];
        short ol = xcur_lo[b * 2048 + 1024 + h];
        xnext_hi[b * 2048 + 1024 + h] = act ? hi16 : oh;        // frozen h1 state
        xnext_lo[b * 2048 + 1024 + h] = act ? lo16 : ol;
        x2_hi[b * 4096 + 3072 + h] = xcur_hi[b * 2048 + h];     // copy h2 state into x2
        x2_lo[b * 4096 + 3072 + h] = xcur_lo[b * 2048 + h];
      } else {
        h2n_hi[b * 1024 + h] = hi16;                            // h2n (fresh) for logits
        h2n_lo[b * 1024 + h] = lo16;
        short oh = xcur_hi[b * 2048 + h];
        short ol = xcur_lo[b * 2048 + h];
        xnext_hi[b * 2048 + h] = act ? hi16 : oh;               // frozen h2 state
        xnext_lo[b * 2048 + h] = act ? lo16 : ol;
      }
    }
  }
}

// ---------------- fused attention tail (ha precomputed by GEMM), one block per batch ----------
__global__ __launch_bounds__(256) void k_attn(
    short* __restrict__ x2_hi, short* __restrict__ x2_lo,
    const float* __restrict__ haB, const float* __restrict__ wa,
    const float* __restrict__ ba, const float* __restrict__ Va,
    const float* __restrict__ Vmat) {
  const int b = blockIdx.x, tid = threadIdx.x;
  __shared__ float ha_sh[256];
  __shared__ float wa_sh[256];
  __shared__ float logit_sh[40];
  __shared__ float p_sh[40];
  ha_sh[tid] = haB[b * 256 + tid];   // includes bha (GEMM bias)
  wa_sh[tid] = wa[tid];
  __syncthreads();
  {  // logit[r] = sum_ph tanh(Va + ha)*wa + ba
    const int r0 = tid >> 3, sl = tid & 7;
    const float ba0 = ba[0];
    for (int r = r0; r < 36; r += 32) {
      const float4v* va4 = (const float4v*)(Va + ((long)b * 36 + r) * 256 + sl * 32);
      float part = 0.f;
      #pragma unroll
      for (int q = 0; q < 8; q++) {
        float4v v4 = va4[q];
        #pragma unroll
        for (int j = 0; j < 4; j++) {
          int ph = sl * 32 + q * 4 + j;
          part += tanhf(v4[j] + ha_sh[ph]) * wa_sh[ph];
        }
      }
      part += __shfl_down(part, 4, 8);
      part += __shfl_down(part, 2, 8);
      part += __shfl_down(part, 1, 8);
      if (sl == 0) logit_sh[r] = part + ba0;
    }
  }
  __syncthreads();
  if (tid < 64) {  // softmax over R=36, one wave
    float v = (tid < 36) ? logit_sh[tid] : -3.4e38f;
    float m = v;
    #pragma unroll
    for (int off = 32; off > 0; off >>= 1) m = fmaxf(m, __shfl_xor(m, off));
    float e = (tid < 36) ? expf(v - m) : 0.f;
    float s = e;
    #pragma unroll
    for (int off = 32; off > 0; off >>= 1) s += __shfl_xor(s, off);
    if (tid < 36) p_sh[tid] = e / s;
  }
  __syncthreads();
  {  // av = sum_r p[r] * Vmat[b,r,:]  (f32 exact) -> split hi/lo into x2
    float av[8];
    #pragma unroll
    for (int j = 0; j < 8; j++) av[j] = 0.f;
    const float* vb = Vmat + (long)b * (36 * 2048) + tid * 8;
    for (int r = 0; r < 36; r++) {
      float p = p_sh[r];
      float4v v0 = *(const float4v*)(vb + (long)r * 2048);
      float4v v1 = *(const float4v*)(vb + (long)r * 2048 + 4);
      #pragma unroll
      for (int j = 0; j < 4; j++) { av[j] += p * v0[j]; av[4 + j] += p * v1[j]; }
    }
    short8v oh, ol;
    #pragma unroll
    for (int j = 0; j < 8; j++) {
      short h = f2bf(av[j]);
      oh[j] = h;
      ol[j] = f2bf(av[j] - bf2f(h));
    }
    *(short8v*)(x2_hi + b * 4096 + tid * 8) = oh;
    *(short8v*)(x2_lo + b * 4096 + tid * 8) = ol;
  }
}

// ---------------- host launcher ----------------
extern "C" void kernel_launch(void* const* d_in, const int* in_sizes, int n_in,
                              void* d_out, int out_size, void* d_ws, size_t ws_size,
                              hipStream_t stream) {
  const float* Vmat = (const float*)d_in[0];
  const float* uv   = (const float*)d_in[2];
  const int* captions = (const int*)d_in[3];
  const int* lengths  = (const int*)d_in[4];
  const float* embW = (const float*)d_in[5];
  const float* Wi1 = (const float*)d_in[6];
  const float* Wh1 = (const float*)d_in[7];
  const float* b1  = (const float*)d_in[8];
  const float* Wi2 = (const float*)d_in[9];
  const float* Wh2 = (const float*)d_in[10];
  const float* b2  = (const float*)d_in[11];
  const float* Wva = (const float*)d_in[12];
  const float* bva = (const float*)d_in[13];
  const float* Wha = (const float*)d_in[14];
  const float* bha = (const float*)d_in[15];
  const float* wa  = (const float*)d_in[16];
  const float* ba  = (const float*)d_in[17];
  const float* Wl  = (const float*)d_in[18];
  const float* bl  = (const float*)d_in[19];
  (void)in_sizes; (void)n_in; (void)out_size; (void)ws_size;

  char* ws = (char*)d_ws;
  size_t off = 0;
  auto alloc = [&](size_t bytes) { void* p = ws + off; off += (bytes + 255) & ~255UL; return p; };
  short* W1dHi = (short*)alloc(4096L * 2048 * 2);   // [Wi1[:, :1024] | Wh1], gate-perm rows
  short* W1dLo = (short*)alloc(4096L * 2048 * 2);
  short* W2dHi = (short*)alloc(4096L * 4096 * 2);   // [Wi2 | Wh2], gate-perm; ALSO hosts W1uv split pre-loop
  short* W2dLo = (short*)alloc(4096L * 4096 * 2);
  short* W1eP  = (short*)alloc(4096L * 1024 * 2);   // Wi1[:, 3072:4096], gate-perm (single)
  short* WlBF  = (short*)alloc(10000L * 1024 * 2);  // single
  short* WvaHi = (short*)alloc(256L * 2048 * 2);
  short* WvaLo = (short*)alloc(256L * 2048 * 2);
  short* WhaHi = (short*)alloc(256L * 1024 * 2);
  short* WhaLo = (short*)alloc(256L * 1024 * 2);
  short* AembBF = (short*)alloc(5120L * 1024 * 2);
  float* VaBuf = (float*)alloc(4608L * 256 * 4);
  float* Z1uvB = (float*)alloc(128L * 4096 * 4);    // includes b1 (perm)
  short* Z1embB = (short*)alloc(5120L * 4096 * 2);  // ALSO hosts Vmat split pre-loop
  float* haB  = (float*)alloc(128L * 256 * 4);
  short* uvHi = (short*)alloc(128L * 2048 * 2);
  short* uvLo = (short*)alloc(128L * 2048 * 2);
  float* b1P = (float*)alloc(4096 * 4);
  float* b2P = (float*)alloc(4096 * 4);
  short* x1Hi = (short*)alloc(2L * 128 * 2048 * 2); // ping-pong [h2 | h1] state, hi plane
  short* x1Lo = (short*)alloc(2L * 128 * 2048 * 2);
  short* x2Hi = (short*)alloc(128L * 4096 * 2);     // [av | h1n | h2]
  short* x2Lo = (short*)alloc(128L * 4096 * 2);
  short* h2nHi = (short*)alloc(128L * 1024 * 2);
  short* h2nLo = (short*)alloc(128L * 1024 * 2);
  float* c1 = (float*)alloc(128L * 1024 * 4);
  float* c2 = (float*)alloc(128L * 1024 * 4);

  // aliased one-time regions
  short* W1uvHi = W2dHi;                 // lifetime ends before W2d perm
  short* W1uvLo = W2dLo;
  short* VmatHi = Z1embB;                // lifetime ends before Z1emb GEMM
  short* VmatLo = Z1embB + 4608L * 2048;

  hipMemsetAsync(x1Hi, 0, 128L * 2048 * 2, stream);
  hipMemsetAsync(x1Lo, 0, 128L * 2048 * 2, stream);
  hipMemsetAsync(c1, 0, 128L * 1024 * 4, stream);
  hipMemsetAsync(c2, 0, 128L * 1024 * 4, stream);

  // conversions / packing
  k_f2bf<<<1024, 256, 0, stream>>>(Wl, WlBF, 10000L * 1024 / 4);
  k_f2bf_split<<<256, 256, 0, stream>>>(Wva, WvaHi, WvaLo, 256L * 2048 / 4);
  k_f2bf_split<<<256, 256, 0, stream>>>(Wha, WhaHi, WhaLo, 256L * 1024 / 4);
  k_f2bf_split<<<1024, 256, 0, stream>>>(Vmat, VmatHi, VmatLo, 128L * 36 * 2048 / 4);
  k_f2bf_split<<<64, 256, 0, stream>>>(uv, uvHi, uvLo, 128L * 2048 / 4);
  k_perm_w_split<<<2048, 256, 0, stream>>>(W1dHi, W1dLo, Wi1, 4096, 0, 1024, Wh1, 1024, 2048);
  k_perm_w_split<<<2048, 256, 0, stream>>>(W1uvHi, W1uvLo, Wi1, 4096, 1024, 2048, Wi1, 4096, 2048);
  k_perm_w<<<1024, 256, 0, stream>>>(W1eP, Wi1, 4096, 3072, 1024, Wi1, 4096, 1024);
  k_perm_bias<<<16, 256, 0, stream>>>(b1P, b1, b2P, b2);
  k_gather_emb<<<2560, 256, 0, stream>>>(AembBF, embW, captions);

  // Va = Vmat @ Wva.T + bva   [4608, 256] f32 (split x split)
  gemm_k<32, EPI_F32, false, true, true><<<dim3(36, 8), 256, 0, stream>>>(
      VmatHi, VmatLo, WvaHi, WvaLo, 2048, 2048, 256, VaBuf, bva,
      nullptr, nullptr, nullptr, nullptr, nullptr, nullptr, nullptr, nullptr, nullptr, nullptr, nullptr,
      nullptr, 0, nullptr, nullptr);
  // Z1uv = uv @ Wi1_uv.T + b1 (perm)   [128, 4096] f32 (split x split)
  gemm_k<32, EPI_F32, false, true, true><<<dim3(1, 128), 256, 0, stream>>>(
      uvHi, uvLo, W1uvHi, W1uvLo, 2048, 2048, 4096, Z1uvB, b1P,
      nullptr, nullptr, nullptr, nullptr, nullptr, nullptr, nullptr, nullptr, nullptr, nullptr, nullptr,
      nullptr, 0, nullptr, nullptr);
  // now safe to overwrite W1uv region with W2d split
  k_perm_w_split<<<2048, 256, 0, stream>>>(W2dHi, W2dLo, Wi2, 3072, 0, 3072, Wh2, 1024, 4096);
  // Z1emb = emb @ Wi1_e.T (perm)  [5120, 4096] bf16 (single; overwrites Vmat split region)
  gemm_k<32, EPI_BF16, false, false, false><<<dim3(40, 128), 256, 0, stream>>>(
      AembBF, nullptr, W1eP, nullptr, 1024, 1024, 4096, Z1embB, nullptr,
      nullptr, nullptr, nullptr, nullptr, nullptr, nullptr, nullptr, nullptr, nullptr, nullptr, nullptr,
      nullptr, 0, nullptr, nullptr);

  for (int t = 0; t < T_; t++) {
    const short* xcH = x1Hi + (size_t)(t & 1) * (128 * 2048);
    const short* xcL = x1Lo + (size_t)(t & 1) * (128 * 2048);
    short* xnH = x1Hi + (size_t)((t + 1) & 1) * (128 * 2048);
    short* xnL = x1Lo + (size_t)((t + 1) & 1) * (128 * 2048);
    // gates1 dynamic part + LSTM1 + h1n/h2 staging  (split x split)
    gemm_k<32, EPI_LSTM1, false, true, true><<<dim3(1, 128), 256, 0, stream>>>(
        xcH, xcL, W1dHi, W1dLo, 2048, 2048, 4096, nullptr, nullptr,
        Z1uvB, Z1embB, c1, xcH, xcL, xnH, xnL, x2Hi, x2Lo, nullptr, nullptr,
        lengths, t, nullptr, nullptr);
    // ha = h1n @ Wha.T + bha   [128, 256] f32 (split x split)
    gemm_k<32, EPI_F32, false, true, true><<<dim3(1, 8), 256, 0, stream>>>(
        x2Hi + 2048, x2Lo + 2048, WhaHi, WhaLo, 1024, 4096, 256, haB, bha,
        nullptr, nullptr, nullptr, nullptr, nullptr, nullptr, nullptr, nullptr, nullptr, nullptr, nullptr,
        nullptr, 0, nullptr, nullptr);
    // attention tail -> av (f32 exact) into x2[:, :2048]
    k_attn<<<128, 256, 0, stream>>>(x2Hi, x2Lo, haB, wa, ba, VaBuf, Vmat);
    // gates2 + LSTM2 -> h2n  (split x split)
    gemm_k<32, EPI_LSTM2, false, true, true><<<dim3(1, 128), 256, 0, stream>>>(
        x2Hi, x2Lo, W2dHi, W2dLo, 4096, 4096, 4096, nullptr, b2P,
        nullptr, nullptr, c2, xcH, xcL, xnH, xnL, nullptr, nullptr, h2nHi, h2nLo,
        lengths, t, nullptr, nullptr);
    // logits + mask -> out[b, t, :]  (split-A only)
    gemm_k<64, EPI_LOGITS, true, true, false><<<dim3(1, 157), 256, 0, stream>>>(
        h2nHi, h2nLo, WlBF, nullptr, 1024, 1024, VOC_, nullptr, nullptr,
        nullptr, nullptr, nullptr, nullptr, nullptr, nullptr, nullptr, nullptr, nullptr, nullptr, nullptr,
        lengths, t, bl, (float*)d_out);
  }
}

// Round 3
// 4781.782 us; speedup vs baseline: 3.0009x; 3.0009x over previous
//
#include <hip/hip_runtime.h>

#define EPI_PART 0
#define EPI_F32D 1
#define EPI_BF16D 2
#define EPI_LOGITS 3

#define T_ 40
#define VOC_ 10000

typedef __attribute__((ext_vector_type(8))) short bf16x8;
typedef __attribute__((ext_vector_type(4))) short short4v;
typedef __attribute__((ext_vector_type(8))) short short8v;
typedef __attribute__((ext_vector_type(4))) float float4v;
typedef __attribute__((ext_vector_type(4))) float f32x4;

__device__ __forceinline__ float bf2f(short s) {
  unsigned u = ((unsigned)(unsigned short)s) << 16;
  float f; __builtin_memcpy(&f, &u, 4); return f;
}
__device__ __forceinline__ short f2bf(float f) {
  unsigned u; __builtin_memcpy(&u, &f, 4);
  u += 0x7FFFu + ((u >> 16) & 1u);
  return (short)(u >> 16);
}
__device__ __forceinline__ float sigm(float x) { return 1.f / (1.f + expf(-x)); }

// packed W layout: W[row][k] at (row>>4)*16*K + (k>>3)*128 + (row&15)*8 + (k&7)
// -> a wave's MFMA B-frag load (lane l: row base+l&15, k kg*8) is one contiguous 1KB block.
__device__ __forceinline__ size_t pkidx(int row, int k, int K) {
  return (size_t)(row >> 4) * 16 * K + (size_t)(k >> 3) * 128 + (size_t)((row & 15) * 8 + (k & 7));
}

// ---------------- packing kernels ----------------

// split f32 -> bf16 hi + lo planes, row-major (for A-side buffers)
__global__ __launch_bounds__(256) void k_f2bf_split(const float* __restrict__ s,
    short* __restrict__ dh, short* __restrict__ dl, long n4) {
  long i = (long)blockIdx.x * 256 + threadIdx.x;
  long stride = (long)gridDim.x * 256;
  for (; i < n4; i += stride) {
    float4v f = ((const float4v*)s)[i];
    short4v oh, ol;
    #pragma unroll
    for (int j = 0; j < 4; j++) {
      short h = f2bf(f[j]); oh[j] = h; ol[j] = f2bf(f[j] - bf2f(h));
    }
    ((short4v*)dh)[i] = oh;
    ((short4v*)dl)[i] = ol;
  }
}

// gate-interleaved row perm p=4h+g (orig row g*1024+h), packed layout, optional lo plane.
__global__ __launch_bounds__(256) void k_permpk(short* __restrict__ dh, short* __restrict__ dl,
    const float* __restrict__ s1, int ld1, int col0, int K1,
    const float* __restrict__ s2, int ld2, int Ktot) {
  int K4 = Ktot >> 2;
  long n4 = 4096L * K4;
  long stride = (long)gridDim.x * 256;
  for (long i = (long)blockIdx.x * 256 + threadIdx.x; i < n4; i += stride) {
    int p = (int)(i / K4);
    int c = ((int)(i % K4)) << 2;
    int orig = ((p & 3) << 10) + (p >> 2);
    const float* src = (c < K1) ? (s1 + (long)orig * ld1 + col0 + c)
                                : (s2 + (long)orig * ld2 + (c - K1));
    float4v f = *(const float4v*)src;
    short4v oh, ol;
    #pragma unroll
    for (int j = 0; j < 4; j++) {
      short h = f2bf(f[j]); oh[j] = h; ol[j] = f2bf(f[j] - bf2f(h));
    }
    size_t d = pkidx(p, c, Ktot);
    *(short4v*)&dh[d] = oh;
    if (dl) *(short4v*)&dl[d] = ol;
  }
}

// natural-row packed conversion with zero padding rows >= Nsrc; optional lo plane.
__global__ __launch_bounds__(256) void k_packpk(short* __restrict__ dh, short* __restrict__ dl,
    const float* __restrict__ src, int ld, int Nr, int Nsrc, int K) {
  int K4 = K >> 2;
  long n4 = (long)Nr * K4;
  long stride = (long)gridDim.x * 256;
  for (long i = (long)blockIdx.x * 256 + threadIdx.x; i < n4; i += stride) {
    int row = (int)(i / K4);
    int c = ((int)(i % K4)) << 2;
    float4v f = {0.f, 0.f, 0.f, 0.f};
    if (row < Nsrc) f = *(const float4v*)(src + (long)row * ld + c);
    short4v oh, ol;
    #pragma unroll
    for (int j = 0; j < 4; j++) {
      short h = f2bf(f[j]); oh[j] = h; ol[j] = f2bf(f[j] - bf2f(h));
    }
    size_t d = pkidx(row, c, K);
    *(short4v*)&dh[d] = oh;
    if (dl) *(short4v*)&dl[d] = ol;
  }
}

__global__ __launch_bounds__(256) void k_perm_bias(float* __restrict__ d1, const float* __restrict__ s1,
                                                   float* __restrict__ d2, const float* __restrict__ s2) {
  int p = blockIdx.x * 256 + threadIdx.x;
  if (p < 4096) {
    int orig = ((p & 3) << 10) + (p >> 2);
    d1[p] = s1[orig];
    d2[p] = s2[orig];
  }
}

// embeddings gather: A_emb[b*T+t, :] = bf16(embed_W[captions[b,t], :])
__global__ __launch_bounds__(256) void k_gather_emb(short* __restrict__ dst, const float* __restrict__ embW,
                                                    const int* __restrict__ cap) {
  int i = blockIdx.x * 256 + threadIdx.x;  // 5120*128
  if (i >= 5120 * 128) return;
  int row = i >> 7, c8 = (i & 127) << 3;
  int tok = cap[row];
  const float4v* s = (const float4v*)(embW + (long)tok * 1024 + c8);
  float4v f0 = s[0], f1 = s[1];
  short8v o;
  #pragma unroll
  for (int j = 0; j < 4; j++) { o[j] = f2bf(f0[j]); o[4 + j] = f2bf(f1[j]); }
  *(short8v*)(dst + (long)row * 1024 + c8) = o;
}

// ---------------- tiled MFMA GEMM: C = A[128,K](hi/lo) @ Wpk[N,K]^T(hi/lo) ----------------
// Grid (N/NT, KS, m_tiles). 256 thr / 4 waves; wave w: mh=w&1 (m-frags mh*4..+3),
// nh=w>>1 (n-frags nh*NFW..+NFW-1). A staged in LDS (dbuf, 64-k stages, XOR-swizzled),
// W loaded as contiguous 1KB/wave frags with one-k-step prefetch. SA: +Alo@W; SW: +A@Wlo.

template<int NT, int EPI, bool SA, bool SW>
__global__ __launch_bounds__(256) void k_gemm2(
    const short* __restrict__ A, const short* __restrict__ Alo, int lda,
    const short* __restrict__ W, const short* __restrict__ Wlo, int K, int Kchunk,
    int N, int Npad,
    float* __restrict__ outf, short* __restrict__ outbf, const float* __restrict__ bias,
    const int* __restrict__ lengths, int t, const float* __restrict__ blg,
    float* __restrict__ out_logits) {
  constexpr int NFW = NT / 32;
  constexpr int LO = 16384;
  __shared__ short sh[(SA ? 4 : 2) * 8192];
  const int tid = threadIdx.x;
  const int lane = tid & 63, wave = tid >> 6;
  const int rif = lane & 15, kg = lane >> 4;
  const int mh = wave & 1, nh = wave >> 1;
  const int n0 = blockIdx.x * NT;
  const int ks = blockIdx.y;
  const int mbase = blockIdx.z * 128;
  const int k0 = ks * Kchunk;
  const int NC = Kchunk >> 6;

  f32x4 acc[4][NFW];
  #pragma unroll
  for (int a = 0; a < 4; a++)
    #pragma unroll
    for (int b = 0; b < NFW; b++) acc[a][b] = (f32x4){0.f, 0.f, 0.f, 0.f};

  // staging geometry: thread covers rows r0 + j*32 (j=0..3), 8 k-shorts at cc0*8
  const int r0 = tid >> 3, cc0 = tid & 7;
  const size_t gstage = (size_t)(mbase + r0) * lda + cc0 * 8;
  const int lstage = r0 * 64 + ((cc0 * 8) ^ ((r0 & 7) << 3));

  const short* wp[NFW]; const short* wlp[NFW];
  #pragma unroll
  for (int nf = 0; nf < NFW; nf++) {
    size_t base = (size_t)(n0 / 16 + nh * NFW + nf) * 16 * K + (size_t)(k0 >> 3) * 128 + lane * 8;
    wp[nf] = W + base;
    if (SW) wlp[nf] = Wlo + base;
  }

  short8v rh[4], rl[4];
  #pragma unroll
  for (int j = 0; j < 4; j++) {
    rh[j] = *(const short8v*)(A + gstage + k0 + (size_t)j * 32 * lda);
    if (SA) rl[j] = *(const short8v*)(Alo + gstage + k0 + (size_t)j * 32 * lda);
  }
  #pragma unroll
  for (int j = 0; j < 4; j++) {
    *(short8v*)&sh[lstage + j * 2048] = rh[j];
    if (SA) *(short8v*)&sh[LO + lstage + j * 2048] = rl[j];
  }
  __syncthreads();

  bf16x8 wv[NFW], wl[NFW];
  #pragma unroll
  for (int nf = 0; nf < NFW; nf++) {
    wv[nf] = *(const bf16x8*)wp[nf]; wp[nf] += 512;
    if (SW) { wl[nf] = *(const bf16x8*)wlp[nf]; wlp[nf] += 512; }
  }

  for (int c = 0; c < NC; c++) {
    if (c + 1 < NC) {
      size_t koff = k0 + (size_t)(c + 1) * 64;
      #pragma unroll
      for (int j = 0; j < 4; j++) {
        rh[j] = *(const short8v*)(A + gstage + koff + (size_t)j * 32 * lda);
        if (SA) rl[j] = *(const short8v*)(Alo + gstage + koff + (size_t)j * 32 * lda);
      }
    }
    const int hbase = (c & 1) * 8192;
    #pragma unroll
    for (int kk = 0; kk < 64; kk += 32) {
      bf16x8 nwv[NFW], nwl[NFW];
      const bool more = (kk == 0) || (c + 1 < NC);
      if (more) {
        #pragma unroll
        for (int nf = 0; nf < NFW; nf++) {
          nwv[nf] = *(const bf16x8*)wp[nf]; wp[nf] += 512;
          if (SW) { nwl[nf] = *(const bf16x8*)wlp[nf]; wlp[nf] += 512; }
        }
      }
      #pragma unroll
      for (int mf = 0; mf < 4; mf++) {
        int row = mh * 64 + mf * 16 + rif;
        int idx = hbase + row * 64 + ((kk + kg * 8) ^ ((rif & 7) << 3));
        bf16x8 ah = *(const bf16x8*)&sh[idx];
        bf16x8 al;
        if (SA) al = *(const bf16x8*)&sh[LO + idx];
        #pragma unroll
        for (int nf = 0; nf < NFW; nf++) {
          acc[mf][nf] = __builtin_amdgcn_mfma_f32_16x16x32_bf16(ah, wv[nf], acc[mf][nf], 0, 0, 0);
          if (SA) acc[mf][nf] = __builtin_amdgcn_mfma_f32_16x16x32_bf16(al, wv[nf], acc[mf][nf], 0, 0, 0);
          if (SW) acc[mf][nf] = __builtin_amdgcn_mfma_f32_16x16x32_bf16(ah, wl[nf], acc[mf][nf], 0, 0, 0);
        }
      }
      if (more) {
        #pragma unroll
        for (int nf = 0; nf < NFW; nf++) { wv[nf] = nwv[nf]; if (SW) wl[nf] = nwl[nf]; }
      }
    }
    __syncthreads();
    if (c + 1 < NC) {
      #pragma unroll
      for (int j = 0; j < 4; j++) {
        *(short8v*)&sh[((c + 1) & 1) * 8192 + lstage + j * 2048] = rh[j];
        if (SA) *(short8v*)&sh[LO + ((c + 1) & 1) * 8192 + lstage + j * 2048] = rl[j];
      }
      __syncthreads();
    }
  }

  #pragma unroll
  for (int mf = 0; mf < 4; mf++) {
    #pragma unroll
    for (int nf = 0; nf < NFW; nf++) {
      int col = n0 + (nh * NFW + nf) * 16 + rif;
      #pragma unroll
      for (int j = 0; j < 4; j++) {
        int row = mh * 64 + mf * 16 + kg * 4 + j;
        float v = acc[mf][nf][j];
        if constexpr (EPI == EPI_PART) {
          outf[((size_t)ks * 128 + row) * Npad + col] = v;
        } else if constexpr (EPI == EPI_F32D) {
          outf[(size_t)(mbase + row) * N + col] = v + (bias ? bias[col] : 0.f);
        } else if constexpr (EPI == EPI_BF16D) {
          outbf[(size_t)(mbase + row) * N + col] = f2bf(v);
        } else {
          if (col < N) {
            bool act = lengths[row] > t;
            out_logits[(size_t)row * (T_ * VOC_) + (size_t)t * VOC_ + col] = act ? (v + blg[col]) : 0.f;
          }
        }
      }
    }
  }
}

// ---------------- LSTM epilogue: sum K-split partials + cell update + state staging ----------
template<int L, int KS>
__global__ __launch_bounds__(256) void k_epi(
    const float* __restrict__ part,
    const float* __restrict__ zuv, const short* __restrict__ zemb, const float* __restrict__ b2p,
    float* __restrict__ cstate,
    const short* __restrict__ xcur_hi, const short* __restrict__ xcur_lo,
    short* __restrict__ xnext_hi, short* __restrict__ xnext_lo,
    short* __restrict__ x2_hi, short* __restrict__ x2_lo,
    short* __restrict__ h2n_hi, short* __restrict__ h2n_lo,
    const int* __restrict__ lengths, int t) {
  int i = blockIdx.x * 256 + threadIdx.x;   // 131072 = 128 b x 1024 h
  int b = i >> 10, h = i & 1023;
  float4v g = {0.f, 0.f, 0.f, 0.f};
  #pragma unroll
  for (int s = 0; s < KS; s++) {
    float4v p = *(const float4v*)&part[((size_t)s * 128 + b) * 4096 + h * 4];
    #pragma unroll
    for (int j = 0; j < 4; j++) g[j] += p[j];
  }
  if constexpr (L == 1) {
    float4v z = *(const float4v*)&zuv[(size_t)b * 4096 + h * 4];   // includes b1
    short4v e = *(const short4v*)&zemb[((size_t)b * T_ + t) * 4096 + h * 4];
    #pragma unroll
    for (int j = 0; j < 4; j++) g[j] += z[j] + bf2f(e[j]);
  } else {
    float4v z = *(const float4v*)&b2p[h * 4];
    #pragma unroll
    for (int j = 0; j < 4; j++) g[j] += z[j];
  }
  float co = cstate[b * 1024 + h];
  float cn = sigm(g[1]) * co + sigm(g[0]) * tanhf(g[2]);
  float hn = sigm(g[3]) * tanhf(cn);
  bool act = lengths[b] > t;
  cstate[b * 1024 + h] = act ? cn : co;
  short hi16 = f2bf(hn);
  short lo16 = f2bf(hn - bf2f(hi16));
  if constexpr (L == 1) {
    x2_hi[b * 4096 + 2048 + h] = hi16;                      // h1n (fresh) for ha/gates2
    x2_lo[b * 4096 + 2048 + h] = lo16;
    short oh = xcur_hi[b * 2048 + 1024 + h];
    short ol = xcur_lo[b * 2048 + 1024 + h];
    xnext_hi[b * 2048 + 1024 + h] = act ? hi16 : oh;        // frozen h1 state
    xnext_lo[b * 2048 + 1024 + h] = act ? lo16 : ol;
    x2_hi[b * 4096 + 3072 + h] = xcur_hi[b * 2048 + h];     // copy h2 state into x2
    x2_lo[b * 4096 + 3072 + h] = xcur_lo[b * 2048 + h];
  } else {
    h2n_hi[b * 1024 + h] = hi16;                            // h2n (fresh) for logits
    h2n_lo[b * 1024 + h] = lo16;
    short oh = xcur_hi[b * 2048 + h];
    short ol = xcur_lo[b * 2048 + h];
    xnext_hi[b * 2048 + h] = act ? hi16 : oh;               // frozen h2 state
    xnext_lo[b * 2048 + h] = act ? lo16 : ol;
  }
}

// ---------------- fused attention tail (ha from K-split partials), one block per batch ----------
__global__ __launch_bounds__(256) void k_attn(
    short* __restrict__ x2_hi, short* __restrict__ x2_lo,
    const float* __restrict__ haPart, const float* __restrict__ bha,
    const float* __restrict__ wa, const float* __restrict__ ba,
    const float* __restrict__ Va, const float* __restrict__ Vmat) {
  const int b = blockIdx.x, tid = threadIdx.x;
  __shared__ float ha_sh[256];
  __shared__ float wa_sh[256];
  __shared__ float logit_sh[40];
  __shared__ float p_sh[40];
  {
    float ha = bha[tid];
    #pragma unroll
    for (int s = 0; s < 4; s++) ha += haPart[((size_t)s * 128 + b) * 256 + tid];
    ha_sh[tid] = ha;
    wa_sh[tid] = wa[tid];
  }
  __syncthreads();
  {  // logit[r] = sum_ph tanh(Va + ha)*wa + ba
    const int r0 = tid >> 3, sl = tid & 7;
    const float ba0 = ba[0];
    for (int r = r0; r < 36; r += 32) {
      const float4v* va4 = (const float4v*)(Va + ((long)b * 36 + r) * 256 + sl * 32);
      float part = 0.f;
      #pragma unroll
      for (int q = 0; q < 8; q++) {
        float4v v4 = va4[q];
        #pragma unroll
        for (int j = 0; j < 4; j++) {
          int ph = sl * 32 + q * 4 + j;
          part += tanhf(v4[j] + ha_sh[ph]) * wa_sh[ph];
        }
      }
      part += __shfl_down(part, 4, 8);
      part += __shfl_down(part, 2, 8);
      part += __shfl_down(part, 1, 8);
      if (sl == 0) logit_sh[r] = part + ba0;
    }
  }
  __syncthreads();
  if (tid < 64) {  // softmax over R=36, one wave
    float v = (tid < 36) ? logit_sh[tid] : -3.4e38f;
    float m = v;
    #pragma unroll
    for (int off = 32; off > 0; off >>= 1) m = fmaxf(m, __shfl_xor(m, off));
    float e = (tid < 36) ? expf(v - m) : 0.f;
    float s = e;
    #pragma unroll
    for (int off = 32; off > 0; off >>= 1) s += __shfl_xor(s, off);
    if (tid < 36) p_sh[tid] = e / s;
  }
  __syncthreads();
  {  // av = sum_r p[r] * Vmat[b,r,:]  (f32 exact) -> split hi/lo into x2
    float av[8];
    #pragma unroll
    for (int j = 0; j < 8; j++) av[j] = 0.f;
    const float* vb = Vmat + (long)b * (36 * 2048) + tid * 8;
    for (int r = 0; r < 36; r++) {
      float p = p_sh[r];
      float4v v0 = *(const float4v*)(vb + (long)r * 2048);
      float4v v1 = *(const float4v*)(vb + (long)r * 2048 + 4);
      #pragma unroll
      for (int j = 0; j < 4; j++) { av[j] += p * v0[j]; av[4 + j] += p * v1[j]; }
    }
    short8v oh, ol;
    #pragma unroll
    for (int j = 0; j < 8; j++) {
      short h = f2bf(av[j]);
      oh[j] = h;
      ol[j] = f2bf(av[j] - bf2f(h));
    }
    *(short8v*)(x2_hi + b * 4096 + tid * 8) = oh;
    *(short8v*)(x2_lo + b * 4096 + tid * 8) = ol;
  }
}

// ---------------- host launcher ----------------
extern "C" void kernel_launch(void* const* d_in, const int* in_sizes, int n_in,
                              void* d_out, int out_size, void* d_ws, size_t ws_size,
                              hipStream_t stream) {
  const float* Vmat = (const float*)d_in[0];
  const float* uv   = (const float*)d_in[2];
  const int* captions = (const int*)d_in[3];
  const int* lengths  = (const int*)d_in[4];
  const float* embW = (const float*)d_in[5];
  const float* Wi1 = (const float*)d_in[6];
  const float* Wh1 = (const float*)d_in[7];
  const float* b1  = (const float*)d_in[8];
  const float* Wi2 = (const float*)d_in[9];
  const float* Wh2 = (const float*)d_in[10];
  const float* b2  = (const float*)d_in[11];
  const float* Wva = (const float*)d_in[12];
  const float* bva = (const float*)d_in[13];
  const float* Wha = (const float*)d_in[14];
  const float* bha = (const float*)d_in[15];
  const float* wa  = (const float*)d_in[16];
  const float* ba  = (const float*)d_in[17];
  const float* Wl  = (const float*)d_in[18];
  const float* bl  = (const float*)d_in[19];
  (void)in_sizes; (void)n_in; (void)out_size; (void)ws_size;

  char* ws = (char*)d_ws;
  size_t off = 0;
  auto alloc = [&](size_t bytes) { void* p = ws + off; off += (bytes + 255) & ~255UL; return p; };
  short* W1dHi = (short*)alloc(4096L * 2048 * 2);   // [Wi1[:, :1024] | Wh1], gate-perm, packed
  short* W1dLo = (short*)alloc(4096L * 2048 * 2);
  short* W2dHi = (short*)alloc(4096L * 4096 * 2);   // [Wi2 | Wh2], gate-perm, packed; hosts W1uv pre-loop
  short* W2dLo = (short*)alloc(4096L * 4096 * 2);
  short* W1ePk = (short*)alloc(4096L * 1024 * 2);   // Wi1[:, 3072:4096], gate-perm, packed (single)
  short* AembBF = (short*)alloc(5120L * 1024 * 2);  // W1ePk+AembBF region later hosts gate partials
  short* WlPK  = (short*)alloc(10048L * 1024 * 2);  // packed single, zero-padded rows 10000..10047
  short* WvaHi = (short*)alloc(256L * 2048 * 2);    // region later hosts haPart
  short* WvaLo = (short*)alloc(256L * 2048 * 2);
  short* WhaHi = (short*)alloc(256L * 1024 * 2);
  short* WhaLo = (short*)alloc(256L * 1024 * 2);
  float* VaBuf = (float*)alloc(4608L * 256 * 4);
  float* Z1uvB = (float*)alloc(128L * 4096 * 4);    // includes b1 (perm)
  short* Z1embB = (short*)alloc(5120L * 4096 * 2);  // hosts Vmat hi/lo split pre-loop
  short* uvHi = (short*)alloc(128L * 2048 * 2);
  short* uvLo = (short*)alloc(128L * 2048 * 2);
  float* b1P = (float*)alloc(4096 * 4);
  float* b2P = (float*)alloc(4096 * 4);
  short* x1Hi = (short*)alloc(2L * 128 * 2048 * 2); // ping-pong [h2 | h1] state
  short* x1Lo = (short*)alloc(2L * 128 * 2048 * 2);
  short* x2Hi = (short*)alloc(128L * 4096 * 2);     // [av | h1n | h2]
  short* x2Lo = (short*)alloc(128L * 4096 * 2);
  short* h2nHi = (short*)alloc(128L * 1024 * 2);
  short* h2nLo = (short*)alloc(128L * 1024 * 2);
  float* c1 = (float*)alloc(128L * 1024 * 4);
  float* c2 = (float*)alloc(128L * 1024 * 4);

  // aliased regions (lifetimes verified by launch order on the stream)
  short* W1uvHi = W2dHi;                  // dead before W2d pack
  short* W1uvLo = W2dLo;
  short* VmatHi = Z1embB;                 // dead before Z1emb GEMM
  short* VmatLo = Z1embB + 4608L * 2048;
  float* partG = (float*)W1ePk;           // [8][128][4096] f32 = 16.8MB <= W1ePk+AembBF (18.9MB)
  float* haPart = (float*)WvaHi;          // [4][128][256] f32 = 0.5MB

  hipMemsetAsync(x1Hi, 0, 128L * 2048 * 2, stream);
  hipMemsetAsync(x1Lo, 0, 128L * 2048 * 2, stream);
  hipMemsetAsync(c1, 0, 128L * 1024 * 4, stream);
  hipMemsetAsync(c2, 0, 128L * 1024 * 4, stream);

  // conversions / packing
  k_packpk<<<2048, 256, 0, stream>>>(WlPK, nullptr, Wl, 1024, 10048, 10000, 1024);
  k_packpk<<<512, 256, 0, stream>>>(WvaHi, WvaLo, Wva, 2048, 256, 256, 2048);
  k_packpk<<<256, 256, 0, stream>>>(WhaHi, WhaLo, Wha, 1024, 256, 256, 1024);
  k_permpk<<<2048, 256, 0, stream>>>(W1dHi, W1dLo, Wi1, 4096, 0, 1024, Wh1, 1024, 2048);
  k_permpk<<<2048, 256, 0, stream>>>(W1uvHi, W1uvLo, Wi1, 4096, 1024, 2048, Wi1, 4096, 2048);
  k_permpk<<<1024, 256, 0, stream>>>(W1ePk, nullptr, Wi1, 4096, 3072, 1024, Wi1, 4096, 1024);
  k_perm_bias<<<16, 256, 0, stream>>>(b1P, b1, b2P, b2);
  k_gather_emb<<<2560, 256, 0, stream>>>(AembBF, embW, captions);
  k_f2bf_split<<<2048, 256, 0, stream>>>(Vmat, VmatHi, VmatLo, 128L * 36 * 2048 / 4);
  k_f2bf_split<<<64, 256, 0, stream>>>(uv, uvHi, uvLo, 128L * 2048 / 4);

  // Va = Vmat @ Wva.T + bva   [4608, 256] f32 (split x split)
  k_gemm2<64, EPI_F32D, true, true><<<dim3(4, 1, 36), 256, 0, stream>>>(
      VmatHi, VmatLo, 2048, WvaHi, WvaLo, 2048, 2048, 256, 256,
      VaBuf, nullptr, bva, nullptr, 0, nullptr, nullptr);
  // Z1uv = uv @ Wi1_uv.T + b1 (perm)   [128, 4096] f32
  k_gemm2<128, EPI_F32D, true, true><<<dim3(32, 1, 1), 256, 0, stream>>>(
      uvHi, uvLo, 2048, W1uvHi, W1uvLo, 2048, 2048, 4096, 4096,
      Z1uvB, nullptr, b1P, nullptr, 0, nullptr, nullptr);
  // W2d pack (overwrites W1uv region)
  k_permpk<<<4096, 256, 0, stream>>>(W2dHi, W2dLo, Wi2, 3072, 0, 3072, Wh2, 1024, 4096);
  // Z1emb = emb @ Wi1_e.T (perm)  [5120, 4096] bf16 (single; overwrites Vmat split region)
  k_gemm2<128, EPI_BF16D, false, false><<<dim3(32, 1, 40), 256, 0, stream>>>(
      AembBF, nullptr, 1024, W1ePk, nullptr, 1024, 1024, 4096, 4096,
      nullptr, Z1embB, nullptr, nullptr, 0, nullptr, nullptr);

  for (int t = 0; t < T_; t++) {
    const short* xcH = x1Hi + (size_t)(t & 1) * (128 * 2048);
    const short* xcL = x1Lo + (size_t)(t & 1) * (128 * 2048);
    short* xnH = x1Hi + (size_t)((t + 1) & 1) * (128 * 2048);
    short* xnL = x1Lo + (size_t)((t + 1) & 1) * (128 * 2048);
    // gates1 dynamic part -> partials [8][128][4096]
    k_gemm2<128, EPI_PART, true, true><<<dim3(32, 8, 1), 256, 0, stream>>>(
        xcH, xcL, 2048, W1dHi, W1dLo, 2048, 256, 4096, 4096,
        partG, nullptr, nullptr, nullptr, 0, nullptr, nullptr);
    // LSTM1 epilogue: sum partials + zuv + zemb -> c1, h1n, state staging
    k_epi<1, 8><<<512, 256, 0, stream>>>(partG, Z1uvB, Z1embB, nullptr, c1,
        xcH, xcL, xnH, xnL, x2Hi, x2Lo, nullptr, nullptr, lengths, t);
    // ha = h1n @ Wha.T (partials [4][128][256])
    k_gemm2<64, EPI_PART, true, true><<<dim3(4, 4, 1), 256, 0, stream>>>(
        x2Hi + 2048, x2Lo + 2048, 4096, WhaHi, WhaLo, 1024, 256, 256, 256,
        haPart, nullptr, nullptr, nullptr, 0, nullptr, nullptr);
    // attention tail -> av into x2[:, :2048]
    k_attn<<<128, 256, 0, stream>>>(x2Hi, x2Lo, haPart, bha, wa, ba, VaBuf, Vmat);
    // gates2 -> partials [8][128][4096]
    k_gemm2<128, EPI_PART, true, true><<<dim3(32, 8, 1), 256, 0, stream>>>(
        x2Hi, x2Lo, 4096, W2dHi, W2dLo, 4096, 512, 4096, 4096,
        partG, nullptr, nullptr, nullptr, 0, nullptr, nullptr);
    // LSTM2 epilogue -> c2, h2n, state staging
    k_epi<2, 8><<<512, 256, 0, stream>>>(partG, nullptr, nullptr, b2P, c2,
        xcH, xcL, xnH, xnL, nullptr, nullptr, h2nHi, h2nLo, lengths, t);
    // logits + mask -> out[b, t, :]   (split-A only)
    k_gemm2<64, EPI_LOGITS, true, false><<<dim3(157, 1, 1), 256, 0, stream>>>(
        h2nHi, h2nLo, 1024, WlPK, nullptr, 1024, 1024, 10000, 10048,
        nullptr, nullptr, nullptr, lengths, t, bl, (float*)d_out);
  }
}

// Round 4
// 4074.943 us; speedup vs baseline: 3.5215x; 1.1735x over previous
//
#include <hip/hip_runtime.h>

#define EPI_PART 0
#define EPI_BF16D 1

#define T_ 40
#define VOC_ 10000

typedef __attribute__((ext_vector_type(8))) short bf16x8;
typedef __attribute__((ext_vector_type(4))) short short4v;
typedef __attribute__((ext_vector_type(8))) short short8v;
typedef __attribute__((ext_vector_type(4))) float float4v;
typedef __attribute__((ext_vector_type(4))) float f32x4;

__device__ __forceinline__ float bf2f(short s) {
  unsigned u = ((unsigned)(unsigned short)s) << 16;
  float f; __builtin_memcpy(&f, &u, 4); return f;
}
__device__ __forceinline__ short f2bf(float f) {
  unsigned u; __builtin_memcpy(&u, &f, 4);
  u += 0x7FFFu + ((u >> 16) & 1u);
  return (short)(u >> 16);
}
__device__ __forceinline__ float sigm(float x) { return 1.f / (1.f + expf(-x)); }

// packed W layout: W[row][k] at (row>>4)*16*K + (k>>3)*128 + (row&15)*8 + (k&7)
__device__ __forceinline__ size_t pkidx(int row, int k, int K) {
  return (size_t)(row >> 4) * 16 * K + (size_t)(k >> 3) * 128 + (size_t)((row & 15) * 8 + (k & 7));
}

// ---------------- packing kernels ----------------

__global__ __launch_bounds__(256) void k_f2bf_split(const float* __restrict__ s,
    short* __restrict__ dh, short* __restrict__ dl, long n4) {
  long i = (long)blockIdx.x * 256 + threadIdx.x;
  long stride = (long)gridDim.x * 256;
  for (; i < n4; i += stride) {
    float4v f = ((const float4v*)s)[i];
    short4v oh, ol;
    #pragma unroll
    for (int j = 0; j < 4; j++) {
      short h = f2bf(f[j]); oh[j] = h; ol[j] = f2bf(f[j] - bf2f(h));
    }
    ((short4v*)dh)[i] = oh;
    ((short4v*)dl)[i] = ol;
  }
}

// gate-interleaved row perm p=4h+g (orig row g*1024+h), packed layout, optional lo plane.
__global__ __launch_bounds__(256) void k_permpk(short* __restrict__ dh, short* __restrict__ dl,
    const float* __restrict__ s1, int ld1, int col0, int K1,
    const float* __restrict__ s2, int ld2, int Ktot) {
  int K4 = Ktot >> 2;
  long n4 = 4096L * K4;
  long stride = (long)gridDim.x * 256;
  for (long i = (long)blockIdx.x * 256 + threadIdx.x; i < n4; i += stride) {
    int p = (int)(i / K4);
    int c = ((int)(i % K4)) << 2;
    int orig = ((p & 3) << 10) + (p >> 2);
    const float* src = (c < K1) ? (s1 + (long)orig * ld1 + col0 + c)
                                : (s2 + (long)orig * ld2 + (c - K1));
    float4v f = *(const float4v*)src;
    short4v oh, ol;
    #pragma unroll
    for (int j = 0; j < 4; j++) {
      short h = f2bf(f[j]); oh[j] = h; ol[j] = f2bf(f[j] - bf2f(h));
    }
    size_t d = pkidx(p, c, Ktot);
    *(short4v*)&dh[d] = oh;
    if (dl) *(short4v*)&dl[d] = ol;
  }
}

// natural-row packed conversion, zero-pad rows >= Nsrc; optional lo plane.
__global__ __launch_bounds__(256) void k_packpk(short* __restrict__ dh, short* __restrict__ dl,
    const float* __restrict__ src, int ld, int Nr, int Nsrc, int K) {
  int K4 = K >> 2;
  long n4 = (long)Nr * K4;
  long stride = (long)gridDim.x * 256;
  for (long i = (long)blockIdx.x * 256 + threadIdx.x; i < n4; i += stride) {
    int row = (int)(i / K4);
    int c = ((int)(i % K4)) << 2;
    float4v f = {0.f, 0.f, 0.f, 0.f};
    if (row < Nsrc) f = *(const float4v*)(src + (long)row * ld + c);
    short4v oh, ol;
    #pragma unroll
    for (int j = 0; j < 4; j++) {
      short h = f2bf(f[j]); oh[j] = h; ol[j] = f2bf(f[j] - bf2f(h));
    }
    size_t d = pkidx(row, c, K);
    *(short4v*)&dh[d] = oh;
    if (dl) *(short4v*)&dl[d] = ol;
  }
}

__global__ __launch_bounds__(256) void k_perm_bias(float* __restrict__ d1, const float* __restrict__ s1,
                                                   float* __restrict__ d2, const float* __restrict__ s2) {
  int p = blockIdx.x * 256 + threadIdx.x;
  if (p < 4096) {
    int orig = ((p & 3) << 10) + (p >> 2);
    d1[p] = s1[orig];
    d2[p] = s2[orig];
  }
}

__global__ __launch_bounds__(256) void k_gather_emb(short* __restrict__ dst, const float* __restrict__ embW,
                                                    const int* __restrict__ cap) {
  int i = blockIdx.x * 256 + threadIdx.x;  // 5120*128
  if (i >= 5120 * 128) return;
  int row = i >> 7, c8 = (i & 127) << 3;
  int tok = cap[row];
  const float4v* s = (const float4v*)(embW + (long)tok * 1024 + c8);
  float4v f0 = s[0], f1 = s[1];
  short8v o;
  #pragma unroll
  for (int j = 0; j < 4; j++) { o[j] = f2bf(f0[j]); o[4 + j] = f2bf(f1[j]); }
  *(short8v*)(dst + (long)row * 1024 + c8) = o;
}

// ---------------- single-wait slab GEMM ----------------
// C[M=128/tile, N] = A @ Wpk^T. NT=64. Grid (Ntiles, KS, Mtiles); Kchunk = NC*128.
// All W frags for the block's K-range preloaded to regs (ring of <=2 slabs);
// A staged per-128k slab into XOR-swizzled LDS. One vm-wait per slab.
// Wave w owns n-frag (n0 + w*16); 8 m-frags cover 128 rows.

template<int NC, bool SA, bool SW, int EPI>
__global__ __launch_bounds__(256) void k_g3(
    const short* __restrict__ A, const short* __restrict__ Alo, int lda,
    const short* __restrict__ W, const short* __restrict__ Wlo, int K,
    int Npad, int Mtot,
    float* __restrict__ outf, short* __restrict__ outbf) {
  __shared__ short sh[SA ? 32768 : 16384];
  const int tid = threadIdx.x;
  const int l = tid & 63, w = tid >> 6;
  const int rif = l & 15, kg = l >> 4;
  const int n0 = blockIdx.x * 64;
  const int k0 = blockIdx.y * NC * 128;
  const int mbase = blockIdx.z * 128;

  f32x4 acc[8];
  #pragma unroll
  for (int m = 0; m < 8; m++) acc[m] = (f32x4){0.f, 0.f, 0.f, 0.f};

  // W register ring (slot = slab & 1)
  bf16x8 wh[2][4], wl[2][4];
  const size_t wtile = (size_t)(n0 / 16 + w) * 16 * K + (size_t)l * 8;

  auto loadW = [&](int c, int slot) {
    size_t base = wtile + (size_t)((k0 + c * 128) >> 3) * 128;
    #pragma unroll
    for (int sk = 0; sk < 4; sk++) {
      wh[slot][sk] = *(const bf16x8*)(W + base + sk * 512);
      if (SW) wl[slot][sk] = *(const bf16x8*)(Wlo + base + sk * 512);
    }
  };
  auto stageA = [&](int c) {
    #pragma unroll
    for (int p = 0; p < (SA ? 2 : 1); p++) {
      const short* src = p ? Alo : A;
      #pragma unroll
      for (int j = 0; j < 8; j++) {
        int row = (j * 4 + w) * 4 + (l >> 4);
        int col = (l & 15) * 8;
        short8v v = *(const short8v*)(src + (size_t)(mbase + row) * lda + k0 + c * 128 + col);
        *(short8v*)&sh[p * 16384 + row * 128 + (col ^ ((row & 7) << 3))] = v;
      }
    }
  };
  auto compute = [&](int slot) {
    #pragma unroll
    for (int sk = 0; sk < 4; sk++) {
      int colb = ((sk * 32 + kg * 8) ^ ((rif & 7) << 3));
      #pragma unroll
      for (int m = 0; m < 8; m++) {
        int idx = (m * 16 + rif) * 128 + colb;
        bf16x8 ah = *(const bf16x8*)&sh[idx];
        acc[m] = __builtin_amdgcn_mfma_f32_16x16x32_bf16(ah, wh[slot][sk], acc[m], 0, 0, 0);
        if (SA) {
          bf16x8 al = *(const bf16x8*)&sh[16384 + idx];
          acc[m] = __builtin_amdgcn_mfma_f32_16x16x32_bf16(al, wh[slot][sk], acc[m], 0, 0, 0);
        }
        if (SW) acc[m] = __builtin_amdgcn_mfma_f32_16x16x32_bf16(ah, wl[slot][sk], acc[m], 0, 0, 0);
      }
    }
  };

  loadW(0, 0);
  stageA(0);
  __syncthreads();
  #pragma unroll
  for (int c = 0; c < NC; c++) {
    if (c + 1 < NC) loadW(c + 1, (c + 1) & 1);
    compute(c & 1);
    if (c + 1 < NC) {
      __syncthreads();
      stageA(c + 1);
      __syncthreads();
    }
  }

  const int col = n0 + w * 16 + rif;
  #pragma unroll
  for (int m = 0; m < 8; m++) {
    #pragma unroll
    for (int j = 0; j < 4; j++) {
      int row = m * 16 + kg * 4 + j;
      if constexpr (EPI == EPI_PART) {
        outf[((size_t)blockIdx.y * Mtot + mbase + row) * Npad + col] = acc[m][j];
      } else {
        outbf[(size_t)(mbase + row) * Npad + col] = f2bf(acc[m][j]);
      }
    }
  }
}

// ---------------- partial sum (+bias) -> f32 ----------------
__global__ __launch_bounds__(256) void k_sum(const float* __restrict__ part,
    float* __restrict__ out, const float* __restrict__ bias,
    long n4, int N4, int KS, long stride4) {
  long i = (long)blockIdx.x * 256 + threadIdx.x;
  if (i >= n4) return;
  float4v a = *(const float4v*)&bias[(i % N4) * 4];
  for (int s = 0; s < KS; s++) {
    float4v p = ((const float4v*)part)[s * stride4 + i];
    #pragma unroll
    for (int j = 0; j < 4; j++) a[j] += p[j];
  }
  ((float4v*)out)[i] = a;
}

// ---------------- LSTM epilogue ----------------
template<int L, int KS>
__global__ __launch_bounds__(256) void k_epi(
    const float* __restrict__ part,
    const float* __restrict__ zuv, const short* __restrict__ zemb, const float* __restrict__ b2p,
    float* __restrict__ cstate,
    const short* __restrict__ xcur_hi, const short* __restrict__ xcur_lo,
    short* __restrict__ xnext_hi, short* __restrict__ xnext_lo,
    short* __restrict__ x2_hi, short* __restrict__ x2_lo,
    short* __restrict__ h2n_hi, short* __restrict__ h2n_lo,
    const int* __restrict__ lengths, int t) {
  int i = blockIdx.x * 256 + threadIdx.x;   // 131072 = 128 b x 1024 h
  int b = i >> 10, h = i & 1023;
  float4v g = {0.f, 0.f, 0.f, 0.f};
  #pragma unroll
  for (int s = 0; s < KS; s++) {
    float4v p = *(const float4v*)&part[((size_t)s * 128 + b) * 4096 + h * 4];
    #pragma unroll
    for (int j = 0; j < 4; j++) g[j] += p[j];
  }
  if constexpr (L == 1) {
    float4v z = *(const float4v*)&zuv[(size_t)b * 4096 + h * 4];   // includes b1
    short4v e = *(const short4v*)&zemb[((size_t)b * T_ + t) * 4096 + h * 4];
    #pragma unroll
    for (int j = 0; j < 4; j++) g[j] += z[j] + bf2f(e[j]);
  } else {
    float4v z = *(const float4v*)&b2p[h * 4];
    #pragma unroll
    for (int j = 0; j < 4; j++) g[j] += z[j];
  }
  float co = cstate[b * 1024 + h];
  float cn = sigm(g[1]) * co + sigm(g[0]) * tanhf(g[2]);
  float hn = sigm(g[3]) * tanhf(cn);
  bool act = lengths[b] > t;
  cstate[b * 1024 + h] = act ? cn : co;
  short hi16 = f2bf(hn);
  short lo16 = f2bf(hn - bf2f(hi16));
  if constexpr (L == 1) {
    x2_hi[b * 4096 + 2048 + h] = hi16;
    x2_lo[b * 4096 + 2048 + h] = lo16;
    short oh = xcur_hi[b * 2048 + 1024 + h];
    short ol = xcur_lo[b * 2048 + 1024 + h];
    xnext_hi[b * 2048 + 1024 + h] = act ? hi16 : oh;
    xnext_lo[b * 2048 + 1024 + h] = act ? lo16 : ol;
    x2_hi[b * 4096 + 3072 + h] = xcur_hi[b * 2048 + h];
    x2_lo[b * 4096 + 3072 + h] = xcur_lo[b * 2048 + h];
  } else {
    h2n_hi[b * 1024 + h] = hi16;
    h2n_lo[b * 1024 + h] = lo16;
    short oh = xcur_hi[b * 2048 + h];
    short ol = xcur_lo[b * 2048 + h];
    xnext_hi[b * 2048 + h] = act ? hi16 : oh;
    xnext_lo[b * 2048 + h] = act ? lo16 : ol;
  }
}

// ---------------- logits epilogue: sum 4 partials + bias + mask -> d_out ----------------
__global__ __launch_bounds__(256) void k_epi_logits(const float* __restrict__ part,
    const float* __restrict__ bl, const int* __restrict__ lengths, int t,
    float* __restrict__ out) {
  int id = blockIdx.x * 256 + threadIdx.x;   // 320000 = 128 b x 2500 col4
  if (id >= 320000) return;
  int b = id / 2500, q = (id % 2500) * 4;
  bool act = lengths[b] > t;
  float4v a = {0.f, 0.f, 0.f, 0.f};
  if (act) {
    a = *(const float4v*)&bl[q];
    #pragma unroll
    for (int s = 0; s < 4; s++) {
      float4v p = *(const float4v*)&part[((size_t)s * 128 + b) * 10048 + q];
      #pragma unroll
      for (int j = 0; j < 4; j++) a[j] += p[j];
    }
  }
  *(float4v*)&out[((size_t)b * T_ + t) * VOC_ + q] = a;
}

// ---------------- fused attention tail, one block per batch ----------------
__global__ __launch_bounds__(256) void k_attn(
    short* __restrict__ x2_hi, short* __restrict__ x2_lo,
    const float* __restrict__ haPart, const float* __restrict__ bha,
    const float* __restrict__ wa, const float* __restrict__ ba,
    const float* __restrict__ Va, const float* __restrict__ Vmat) {
  const int b = blockIdx.x, tid = threadIdx.x;
  __shared__ float ha_sh[256];
  __shared__ float wa_sh[256];
  __shared__ float logit_sh[40];
  __shared__ float p_sh[40];
  {
    float ha = bha[tid];
    #pragma unroll
    for (int s = 0; s < 8; s++) ha += haPart[((size_t)s * 128 + b) * 256 + tid];
    ha_sh[tid] = ha;
    wa_sh[tid] = wa[tid];
  }
  __syncthreads();
  {
    const int r0 = tid >> 3, sl = tid & 7;
    const float ba0 = ba[0];
    for (int r = r0; r < 36; r += 32) {
      const float4v* va4 = (const float4v*)(Va + ((long)b * 36 + r) * 256 + sl * 32);
      float part = 0.f;
      #pragma unroll
      for (int q = 0; q < 8; q++) {
        float4v v4 = va4[q];
        #pragma unroll
        for (int j = 0; j < 4; j++) {
          int ph = sl * 32 + q * 4 + j;
          part += tanhf(v4[j] + ha_sh[ph]) * wa_sh[ph];
        }
      }
      part += __shfl_down(part, 4, 8);
      part += __shfl_down(part, 2, 8);
      part += __shfl_down(part, 1, 8);
      if (sl == 0) logit_sh[r] = part + ba0;
    }
  }
  __syncthreads();
  if (tid < 64) {
    float v = (tid < 36) ? logit_sh[tid] : -3.4e38f;
    float m = v;
    #pragma unroll
    for (int off = 32; off > 0; off >>= 1) m = fmaxf(m, __shfl_xor(m, off));
    float e = (tid < 36) ? expf(v - m) : 0.f;
    float s = e;
    #pragma unroll
    for (int off = 32; off > 0; off >>= 1) s += __shfl_xor(s, off);
    if (tid < 36) p_sh[tid] = e / s;
  }
  __syncthreads();
  {
    float av[8];
    #pragma unroll
    for (int j = 0; j < 8; j++) av[j] = 0.f;
    const float* vb = Vmat + (long)b * (36 * 2048) + tid * 8;
    for (int r = 0; r < 36; r++) {
      float p = p_sh[r];
      float4v v0 = *(const float4v*)(vb + (long)r * 2048);
      float4v v1 = *(const float4v*)(vb + (long)r * 2048 + 4);
      #pragma unroll
      for (int j = 0; j < 4; j++) { av[j] += p * v0[j]; av[4 + j] += p * v1[j]; }
    }
    short8v oh, ol;
    #pragma unroll
    for (int j = 0; j < 8; j++) {
      short h = f2bf(av[j]);
      oh[j] = h;
      ol[j] = f2bf(av[j] - bf2f(h));
    }
    *(short8v*)(x2_hi + b * 4096 + tid * 8) = oh;
    *(short8v*)(x2_lo + b * 4096 + tid * 8) = ol;
  }
}

// ---------------- host launcher ----------------
extern "C" void kernel_launch(void* const* d_in, const int* in_sizes, int n_in,
                              void* d_out, int out_size, void* d_ws, size_t ws_size,
                              hipStream_t stream) {
  const float* Vmat = (const float*)d_in[0];
  const float* uv   = (const float*)d_in[2];
  const int* captions = (const int*)d_in[3];
  const int* lengths  = (const int*)d_in[4];
  const float* embW = (const float*)d_in[5];
  const float* Wi1 = (const float*)d_in[6];
  const float* Wh1 = (const float*)d_in[7];
  const float* b1  = (const float*)d_in[8];
  const float* Wi2 = (const float*)d_in[9];
  const float* Wh2 = (const float*)d_in[10];
  const float* b2  = (const float*)d_in[11];
  const float* Wva = (const float*)d_in[12];
  const float* bva = (const float*)d_in[13];
  const float* Wha = (const float*)d_in[14];
  const float* bha = (const float*)d_in[15];
  const float* wa  = (const float*)d_in[16];
  const float* ba  = (const float*)d_in[17];
  const float* Wl  = (const float*)d_in[18];
  const float* bl  = (const float*)d_in[19];
  (void)in_sizes; (void)n_in; (void)out_size; (void)ws_size;

  char* ws = (char*)d_ws;
  size_t off = 0;
  auto alloc = [&](size_t bytes) { void* p = ws + off; off += (bytes + 255) & ~255UL; return p; };
  short* W1dHi = (short*)alloc(4096L * 2048 * 2);   // gate-perm packed [Wi1[:, :1024] | Wh1]
  short* W1dLo = (short*)alloc(4096L * 2048 * 2);
  short* W2dHi = (short*)alloc(4096L * 4096 * 2);   // gate-perm packed [Wi2 | Wh2]; staging arena pre-loop
  short* W2dLo = (short*)alloc(4096L * 4096 * 2);
  short* WlPK  = (short*)alloc(10048L * 1024 * 2);  // packed single, zero-padded
  short* WhaHi = (short*)alloc(256L * 1024 * 2);
  short* WhaLo = (short*)alloc(256L * 1024 * 2);
  float* VaBuf = (float*)alloc(4608L * 256 * 4);
  float* Z1uvB = (float*)alloc(128L * 4096 * 4);    // includes b1 (perm)
  short* Z1embB = (short*)alloc(5120L * 4096 * 2);  // hosts Vmat hi/lo split pre-loop
  float* partG = (float*)alloc(16L * 128 * 4096 * 4); // 33.5MB: gate/logits partials; W1e+Aemb pre-loop
  float* haPart = (float*)alloc(8L * 128 * 256 * 4);
  float* b1P = (float*)alloc(4096 * 4);
  float* b2P = (float*)alloc(4096 * 4);
  short* x1Hi = (short*)alloc(2L * 128 * 2048 * 2);
  short* x1Lo = (short*)alloc(2L * 128 * 2048 * 2);
  short* x2Hi = (short*)alloc(128L * 4096 * 2);     // [av | h1n | h2]
  short* x2Lo = (short*)alloc(128L * 4096 * 2);
  short* h2nHi = (short*)alloc(128L * 1024 * 2);
  short* h2nLo = (short*)alloc(128L * 1024 * 2);
  float* c1 = (float*)alloc(128L * 1024 * 4);
  float* c2 = (float*)alloc(128L * 1024 * 4);

  // ---- aliased staging regions ----
  // W2d arena (67 MB), all dead before W2d pack:
  short* W1uvHi = W2dHi;                                  // [0, 16.8M)
  short* W1uvLo = W2dHi + 4096L * 2048;                   // [16.8, 33.5M)
  float* zuvPart = (float*)(W2dHi + 4096L * 4096);        // [33.5, 50.3M)  Z1uv partials [8][128][4096]
  short* uvHi = W2dHi + 4096L * 4096 + 4096L * 2048 + 2097152;       // ~[52.4M)
  short* uvLo = uvHi + 128L * 2048;
  short* WvaHi = uvLo + 128L * 2048;                      // 1 MB
  short* WvaLo = WvaHi + 256L * 2048;
  float* vaPart = (float*)W2dHi;                          // [0, 37.7M) Va partials [8][4608][256] (after W1uv dead)
  // partG arena pre-loop:
  short* W1ePk = (short*)partG;                           // 8.4 MB
  short* AembBF = (short*)partG + 4096L * 1024;           // 10.5 MB
  // Z1emb arena pre-loop:
  short* VmatHi = Z1embB;                                 // 18.9 MB
  short* VmatLo = Z1embB + 4608L * 2048;

  hipMemsetAsync(x1Hi, 0, 2L * 128 * 2048 * 2, stream);
  hipMemsetAsync(x1Lo, 0, 2L * 128 * 2048 * 2, stream);
  hipMemsetAsync(c1, 0, 128L * 1024 * 4, stream);
  hipMemsetAsync(c2, 0, 128L * 1024 * 4, stream);

  // ---- packing ----
  k_packpk<<<2048, 256, 0, stream>>>(WlPK, nullptr, Wl, 1024, 10048, 10000, 1024);
  k_packpk<<<256, 256, 0, stream>>>(WhaHi, WhaLo, Wha, 1024, 256, 256, 1024);
  k_packpk<<<512, 256, 0, stream>>>(WvaHi, WvaLo, Wva, 2048, 256, 256, 2048);
  k_permpk<<<2048, 256, 0, stream>>>(W1dHi, W1dLo, Wi1, 4096, 0, 1024, Wh1, 1024, 2048);
  k_permpk<<<2048, 256, 0, stream>>>(W1uvHi, W1uvLo, Wi1, 4096, 1024, 2048, Wi1, 4096, 2048);
  k_permpk<<<1024, 256, 0, stream>>>(W1ePk, nullptr, Wi1, 4096, 3072, 1024, Wi1, 4096, 1024);
  k_perm_bias<<<16, 256, 0, stream>>>(b1P, b1, b2P, b2);
  k_gather_emb<<<2560, 256, 0, stream>>>(AembBF, embW, captions);
  k_f2bf_split<<<2048, 256, 0, stream>>>(Vmat, VmatHi, VmatLo, 128L * 36 * 2048 / 4);
  k_f2bf_split<<<64, 256, 0, stream>>>(uv, uvHi, uvLo, 128L * 2048 / 4);

  // Z1uv = uv @ W1uv^T + b1 (perm): partials then sum
  k_g3<2, true, true, EPI_PART><<<dim3(64, 8, 1), 256, 0, stream>>>(
      uvHi, uvLo, 2048, W1uvHi, W1uvLo, 2048, 4096, 128, zuvPart, nullptr);
  k_sum<<<512, 256, 0, stream>>>(zuvPart, Z1uvB, b1P, 131072, 1024, 8, 131072);
  // Va = Vmat @ Wva^T + bva  (W1uv now dead; vaPart overlays it)
  k_g3<2, true, true, EPI_PART><<<dim3(4, 8, 36), 256, 0, stream>>>(
      VmatHi, VmatLo, 2048, WvaHi, WvaLo, 2048, 256, 4608, vaPart, nullptr);
  k_sum<<<1152, 256, 0, stream>>>(vaPart, VaBuf, bva, 294912, 64, 8, 294912);
  // W2d pack (overwrites the whole staging arena)
  k_permpk<<<4096, 256, 0, stream>>>(W2dHi, W2dLo, Wi2, 3072, 0, 3072, Wh2, 1024, 4096);
  // Z1emb = emb @ W1e^T (single-plane, direct bf16; frees Vmat split region)
  k_g3<8, false, false, EPI_BF16D><<<dim3(64, 1, 40), 256, 0, stream>>>(
      AembBF, nullptr, 1024, W1ePk, nullptr, 1024, 4096, 5120, nullptr, Z1embB);

  for (int t = 0; t < T_; t++) {
    const short* xcH = x1Hi + (size_t)(t & 1) * (128 * 2048);
    const short* xcL = x1Lo + (size_t)(t & 1) * (128 * 2048);
    short* xnH = x1Hi + (size_t)((t + 1) & 1) * (128 * 2048);
    short* xnL = x1Lo + (size_t)((t + 1) & 1) * (128 * 2048);
    // gates1 dynamic part -> partials [8][128][4096]
    k_g3<2, true, true, EPI_PART><<<dim3(64, 8, 1), 256, 0, stream>>>(
        xcH, xcL, 2048, W1dHi, W1dLo, 2048, 4096, 128, partG, nullptr);
    k_epi<1, 8><<<512, 256, 0, stream>>>(partG, Z1uvB, Z1embB, nullptr, c1,
        xcH, xcL, xnH, xnL, x2Hi, x2Lo, nullptr, nullptr, lengths, t);
    // ha partials [8][128][256]
    k_g3<1, true, true, EPI_PART><<<dim3(4, 8, 1), 256, 0, stream>>>(
        x2Hi + 2048, x2Lo + 2048, 4096, WhaHi, WhaLo, 1024, 256, 128, haPart, nullptr);
    k_attn<<<128, 256, 0, stream>>>(x2Hi, x2Lo, haPart, bha, wa, ba, VaBuf, Vmat);
    // gates2 -> partials [16][128][4096]
    k_g3<2, true, true, EPI_PART><<<dim3(64, 16, 1), 256, 0, stream>>>(
        x2Hi, x2Lo, 4096, W2dHi, W2dLo, 4096, 4096, 128, partG, nullptr);
    k_epi<2, 16><<<512, 256, 0, stream>>>(partG, nullptr, nullptr, b2P, c2,
        xcH, xcL, xnH, xnL, nullptr, nullptr, h2nHi, h2nLo, lengths, t);
    // logits -> partials [4][128][10048] (reuse partG), then epilogue
    k_g3<2, true, false, EPI_PART><<<dim3(157, 4, 1), 256, 0, stream>>>(
        h2nHi, h2nLo, 1024, WlPK, nullptr, 1024, 10048, 128, partG, nullptr);
    k_epi_logits<<<1250, 256, 0, stream>>>(partG, bl, lengths, t, (float*)d_out);
  }
}